// Round 16
// baseline (920.588 us; speedup 1.0000x reference)
//
#include <hip/hip_runtime.h>

#define N_NODES 50000
#define N_EDGES 800000
#define N_GRAPHS 64
#define INDIM 128
#define HID 256
#define OUTD 10
#define NREP 8            // stats replicas (atomic-contention spread)
#define STSTRIDE (NREP * 512)

typedef __attribute__((ext_vector_type(8))) short bf16x8;
typedef __attribute__((ext_vector_type(4))) float f32x4;
typedef __attribute__((ext_vector_type(4))) unsigned short u16x4;
typedef __attribute__((ext_vector_type(8))) unsigned short u16x8;

__device__ __forceinline__ float b2f(unsigned short u) {
  union { unsigned int i; float f; } c;
  c.i = ((unsigned int)u) << 16;
  return c.f;
}
__device__ __forceinline__ unsigned short f2b(float f) {
  union { float f; unsigned int i; } c;
  c.f = f;
  unsigned int x = c.i + 0x7FFFu + ((c.i >> 16) & 1u);  // RNE
  return (unsigned short)(x >> 16);
}

__device__ __forceinline__ void gload16(const void* g, void* l) {
  __builtin_amdgcn_global_load_lds(
      (const __attribute__((address_space(1))) unsigned int*)g,
      (__attribute__((address_space(3))) unsigned int*)l, 16, 0, 0);
}

// ---------------- CSR build ----------------
__global__ void k_hist(const int* __restrict__ dst, int* __restrict__ deg) {
  int e = blockIdx.x * blockDim.x + threadIdx.x;
  if (e < N_EDGES) atomicAdd(&deg[dst[e]], 1);
}

#define SCAN_NB ((N_NODES + 255) / 256)  // 196

__global__ __launch_bounds__(256) void k_scan1(const int* __restrict__ deg,
                                               int* __restrict__ bsum) {
  int i = blockIdx.x * 256 + threadIdx.x;
  int v = (i < N_NODES) ? deg[i] : 0;
#pragma unroll
  for (int m = 1; m < 64; m <<= 1) v += __shfl_xor(v, m, 64);
  __shared__ int ws[4];
  if ((threadIdx.x & 63) == 0) ws[threadIdx.x >> 6] = v;
  __syncthreads();
  if (threadIdx.x == 0) bsum[blockIdx.x] = ws[0] + ws[1] + ws[2] + ws[3];
}

__global__ __launch_bounds__(256) void k_scan2(const int* __restrict__ bsum,
                                               int* __restrict__ boff) {
  __shared__ int s[256];
  int t = threadIdx.x;
  s[t] = (t < SCAN_NB) ? bsum[t] : 0;
  __syncthreads();
  for (int o = 1; o < 256; o <<= 1) {
    int v = (t >= o) ? s[t - o] : 0;
    __syncthreads();
    s[t] += v;
    __syncthreads();
  }
  if (t < SCAN_NB) boff[t] = (t == 0) ? 0 : s[t - 1];
}

__global__ __launch_bounds__(256) void k_scan3(const int* __restrict__ deg,
                                               const int* __restrict__ boff,
                                               int* __restrict__ rowptr,
                                               int* __restrict__ cursor) {
  __shared__ int s[256];
  int t = threadIdx.x;
  int i = blockIdx.x * 256 + t;
  int v = (i < N_NODES) ? deg[i] : 0;
  s[t] = v;
  __syncthreads();
  for (int o = 1; o < 256; o <<= 1) {
    int w = (t >= o) ? s[t - o] : 0;
    __syncthreads();
    s[t] += w;
    __syncthreads();
  }
  int excl = ((t == 0) ? 0 : s[t - 1]) + boff[blockIdx.x];
  if (i < N_NODES) {
    rowptr[i] = excl;
    cursor[i] = excl;
    if (i == N_NODES - 1) rowptr[N_NODES] = excl + v;
  }
}

__global__ void k_scatter(const int* __restrict__ src, const int* __restrict__ dst,
                          int* __restrict__ cursor, int* __restrict__ csr) {
  int e = blockIdx.x * blockDim.x + threadIdx.x;
  if (e < N_EDGES) {
    int pos = atomicAdd(&cursor[dst[e]], 1);
    csr[pos] = src[e];
  }
}

// ------- all weight transposes in one kernel: W[K][256] f32 -> Wt[256][K] bf16 -----
__global__ __launch_bounds__(256) void k_wt_all(const float* __restrict__ w01,
                                                const float* __restrict__ w02,
                                                const float* __restrict__ ws1,
                                                const float* __restrict__ ws2,
                                                unsigned short* __restrict__ o01,
                                                unsigned short* __restrict__ o02,
                                                unsigned short* __restrict__ os1,
                                                unsigned short* __restrict__ os2) {
  int o = blockIdx.x * 256 + threadIdx.x;
  if (o < 32768) {  // mlp0_w1: K=128
    int c = o >> 7, k = o & 127;
    o01[o] = f2b(w01[k * HID + c]);
    return;
  }
  o -= 32768;
  if (o < 65536) {  // mlp0_w2: K=256
    int c = o >> 8, k = o & 255;
    o02[o] = f2b(w02[k * HID + c]);
    return;
  }
  o -= 65536;
  if (o < 3 * 65536) {  // mlps_w1[3]
    int loc = o & 65535;
    int c = loc >> 8, k = loc & 255;
    os1[o] = f2b(ws1[(size_t)(o >> 16) * 65536 + k * HID + c]);
    return;
  }
  o -= 3 * 65536;
  {
    int loc = o & 65535;
    int c = loc >> 8, k = loc & 255;
    os2[o] = f2b(ws2[(size_t)(o >> 16) * 65536 + k * HID + c]);
  }
}
#define WT_TOTAL (32768 + 65536 + 6 * 65536)  // 491520

// ---------------- SpMM (pure gather-sum) with VALUE prefetch --------------------
template <int DIM>
__global__ __launch_bounds__(256) void k_spmm5(const unsigned short* __restrict__ h,
                                               const int* __restrict__ rowptr,
                                               const int* __restrict__ csr,
                                               unsigned short* __restrict__ out) {
  constexpr int RL = DIM / 8;  // lanes per row (16B each)
  constexpr int NG = 64 / RL;  // concurrent row streams per wave
  const int lane = threadIdx.x & 63;
  const int node = blockIdx.x * 4 + (threadIdx.x >> 6);
  const int grp = lane / RL;
  const int cbase = (lane % RL) * 8;
  const int b = rowptr[node], e = rowptr[node + 1];
  const int count = e - b + 1;  // virtual list: [self] + neighbors
  float acc[8] = {};
  int j = grp;
  int r0 = 0, r1 = 0, r2 = 0, r3 = 0;
  u16x8 v0, v1, v2, v3;
  bool have = (j + 3 * NG < count);
  if (have) {
    r0 = (j == 0) ? node : csr[b + j - 1];
    r1 = csr[b + j + NG - 1];
    r2 = csr[b + j + 2 * NG - 1];
    r3 = csr[b + j + 3 * NG - 1];
    v0 = *(const u16x8*)(h + (size_t)r0 * DIM + cbase);
    v1 = *(const u16x8*)(h + (size_t)r1 * DIM + cbase);
    v2 = *(const u16x8*)(h + (size_t)r2 * DIM + cbase);
    v3 = *(const u16x8*)(h + (size_t)r3 * DIM + cbase);
  }
  while (have) {
    int jn = j + 4 * NG;
    bool haven = (jn + 3 * NG < count);
    u16x8 w0, w1, w2, w3;
    if (haven) {
      int n0 = csr[b + jn - 1];
      int n1 = csr[b + jn + NG - 1];
      int n2 = csr[b + jn + 2 * NG - 1];
      int n3 = csr[b + jn + 3 * NG - 1];
      w0 = *(const u16x8*)(h + (size_t)n0 * DIM + cbase);
      w1 = *(const u16x8*)(h + (size_t)n1 * DIM + cbase);
      w2 = *(const u16x8*)(h + (size_t)n2 * DIM + cbase);
      w3 = *(const u16x8*)(h + (size_t)n3 * DIM + cbase);
    }
#pragma unroll
    for (int q = 0; q < 8; ++q)
      acc[q] += (b2f(v0[q]) + b2f(v1[q])) + (b2f(v2[q]) + b2f(v3[q]));
    v0 = w0; v1 = w1; v2 = w2; v3 = w3;
    j = jn;
    have = haven;
  }
  for (; j < count; j += NG) {
    int rr = (j == 0) ? node : csr[b + j - 1];
    u16x8 t = *(const u16x8*)(h + (size_t)rr * DIM + cbase);
#pragma unroll
    for (int q = 0; q < 8; ++q) acc[q] += b2f(t[q]);
  }
#pragma unroll
  for (int m = RL; m < 64; m <<= 1)
#pragma unroll
    for (int q = 0; q < 8; ++q) acc[q] += __shfl_xor(acc[q], m, 64);
  if (grp == 0) {
    u16x8 o;
#pragma unroll
    for (int q = 0; q < 8; ++q) o[q] = f2b(acc[q]);
    *(u16x8*)(out + (size_t)node * DIM + cbase) = o;
  }
}

// ------- MFMA GEMM, BM=128 x BN=128, dbuf, XCD-swizzled 1D grid, repl-stats -------
template <int K, bool FUSEBN>
__global__ __launch_bounds__(256) void k_gemm8(const unsigned short* __restrict__ A,
                                               const unsigned short* __restrict__ Wt,
                                               const float* __restrict__ bias,
                                               const float* __restrict__ stIn,
                                               const float* __restrict__ gIn,
                                               const float* __restrict__ bIn,
                                               float* __restrict__ stout,
                                               unsigned short* __restrict__ C, int M) {
  constexpr int NT = K / 64;
  __shared__ short As[2][128 * 64];  // 2 x 16 KB
  __shared__ short Bs[2][128 * 64];  // 2 x 16 KB
  __shared__ float s_sum[128], s_sqs[128];
  __shared__ float s_sc[256], s_sh[256];
  const int tid = threadIdx.x;
  const int lane = tid & 63;
  const int wv = tid >> 6;
  const int wm = wv >> 1, wn = wv & 1;  // 2x2 waves, 64x64 quadrant each
  const int l16 = lane & 15, lh = lane >> 4;
  // bijective XCD swizzle: contiguous wgid chunk per XCD
  const int nwg = gridDim.x;
  const int q8 = nwg >> 3, r8 = nwg & 7;
  const int xcd = blockIdx.x & 7, idx8 = blockIdx.x >> 3;
  const int wgid = (xcd < r8 ? xcd * (q8 + 1) : r8 * (q8 + 1) + (xcd - r8) * q8) + idx8;
  const int rB = (wgid >> 1) * 128;
  const int cB = (wgid & 1) * 128;
  f32x4 acc[4][4] = {};
  if (tid < 128) {
    s_sum[tid] = 0.f;
    s_sqs[tid] = 0.f;
  }
  if constexpr (FUSEBN) {
    const float invM = 1.0f / N_NODES;
    float ssum = 0.f, ssq = 0.f;
#pragma unroll
    for (int r2 = 0; r2 < NREP; ++r2) {
      ssum += stIn[r2 * 512 + tid];
      ssq += stIn[r2 * 512 + 256 + tid];
    }
    float mean = ssum * invM;
    float var = ssq * invM - mean * mean;
    float s = gIn[tid] * rsqrtf(var + 1e-5f);
    s_sc[tid] = s;
    s_sh[tid] = bIn[tid] - mean * s;
    __syncthreads();
  }

  auto stageB = [&](int kt, int buf) {
#pragma unroll
    for (int it = 0; it < 4; ++it) {
      int s2 = it * 256 + tid;
      int r = s2 >> 3, g = s2 & 7;
      int gs = g ^ (r & 7);
      gload16(Wt + (size_t)(cB + r) * K + kt * 64 + gs * 8, &Bs[buf][s2 * 8]);
    }
  };
  auto stageA_direct = [&](int kt, int buf) {
#pragma unroll
    for (int it = 0; it < 4; ++it) {
      int s = it * 256 + tid;
      int r = s >> 3, g = s & 7;
      int gs = g ^ (r & 7);
      int row = rB + r;
      if (row > M - 1) row = M - 1;
      gload16(A + (size_t)row * K + kt * 64 + gs * 8, &As[buf][s * 8]);
    }
  };
  auto loadA_reg = [&](int kt, u16x8* va) {
#pragma unroll
    for (int it = 0; it < 4; ++it) {
      int s = it * 256 + tid;
      int r = s >> 3, g = s & 7;
      int gs = g ^ (r & 7);
      int row = rB + r;
      if (row > M - 1) row = M - 1;
      va[it] = *(const u16x8*)(A + (size_t)row * K + kt * 64 + gs * 8);
    }
  };
  auto writeA_bn = [&](int kt, const u16x8* va, int buf) {
#pragma unroll
    for (int it = 0; it < 4; ++it) {
      int s = it * 256 + tid;
      int r = s >> 3, g = s & 7;
      int gs = g ^ (r & 7);
      int ch0 = kt * 64 + gs * 8;
      u16x8 o;
#pragma unroll
      for (int q = 0; q < 8; ++q) {
        float f = b2f(va[it][q]) * s_sc[ch0 + q] + s_sh[ch0 + q];
        o[q] = f2b(f > 0.f ? f : 0.f);
      }
      *(u16x8*)&As[buf][s * 8] = o;
    }
  };
  auto compute = [&](int buf) {
#pragma unroll
    for (int kh = 0; kh < 2; ++kh) {
      bf16x8 af[4], bfr[4];
      const int gsw = (kh * 4 + lh) ^ (l16 & 7);
#pragma unroll
      for (int m = 0; m < 4; ++m) {
        int row = wm * 64 + m * 16 + l16;
        af[m] = *(const bf16x8*)&As[buf][row * 64 + gsw * 8];
      }
#pragma unroll
      for (int n = 0; n < 4; ++n) {
        int col = wn * 64 + n * 16 + l16;
        bfr[n] = *(const bf16x8*)&Bs[buf][col * 64 + gsw * 8];
      }
#pragma unroll
      for (int m = 0; m < 4; ++m)
#pragma unroll
        for (int n = 0; n < 4; ++n)
          acc[m][n] =
              __builtin_amdgcn_mfma_f32_16x16x32_bf16(af[m], bfr[n], acc[m][n], 0, 0, 0);
    }
  };

  // prologue: stage tile 0 into buf 0
  stageB(0, 0);
  if constexpr (!FUSEBN) {
    stageA_direct(0, 0);
  } else {
    u16x8 va0[4];
    loadA_reg(0, va0);
    writeA_bn(0, va0, 0);
  }
  __syncthreads();

  for (int kt = 0; kt < NT; ++kt) {
    const int cur = kt & 1, nxt = cur ^ 1;
    u16x8 va[4];
    const bool more = (kt + 1 < NT);
    if (more) {
      stageB(kt + 1, nxt);
      if constexpr (!FUSEBN) {
        stageA_direct(kt + 1, nxt);
      } else {
        loadA_reg(kt + 1, va);
      }
    }
    compute(cur);
    if constexpr (FUSEBN) {
      if (more) writeA_bn(kt + 1, va, nxt);
    }
    __syncthreads();
  }

  // epilogue: n-inner stores (write-combine friendly) + replicated stats
  float bv[4], ps[4] = {}, pq[4] = {};
#pragma unroll
  for (int n = 0; n < 4; ++n) bv[n] = bias[cB + wn * 64 + n * 16 + l16];
#pragma unroll
  for (int m = 0; m < 4; ++m) {
#pragma unroll
    for (int r = 0; r < 4; ++r) {
      int row = rB + wm * 64 + m * 16 + lh * 4 + r;
      if (row < M) {
#pragma unroll
        for (int n = 0; n < 4; ++n) {
          float val = acc[m][n][r] + bv[n];
          ps[n] += val;
          pq[n] += val * val;
          C[(size_t)row * HID + cB + wn * 64 + n * 16 + l16] = f2b(val);
        }
      }
    }
  }
#pragma unroll
  for (int n = 0; n < 4; ++n) {
    int colL = wn * 64 + n * 16 + l16;
    atomicAdd(&s_sum[colL], ps[n]);
    atomicAdd(&s_sqs[colL], pq[n]);
  }
  __syncthreads();
  if (tid < 128) {
    float* so = stout + (blockIdx.x & (NREP - 1)) * 512;  // replica spread
    atomicAdd(&so[cB + tid], s_sum[tid]);
    atomicAdd(&so[256 + cB + tid], s_sqs[tid]);
  }
}

// ------- pool over relu(bn(raw)) + optional side-output of applied bf16 h ---------
// 64 rows per block (grid 782, ~3 blocks/CU): wave wv owns rows
// [blk*64+wv*16, +16), each 32-lane stream (grp) walks 8 rows (r += 2).
template <bool WRITEAPP>
__global__ __launch_bounds__(256) void k_pool_apply(const unsigned short* __restrict__ H,
                                                    const int* __restrict__ gid,
                                                    const float* __restrict__ st,
                                                    const float* __restrict__ g,
                                                    const float* __restrict__ bb,
                                                    float* __restrict__ gp,
                                                    unsigned short* __restrict__ happ) {
  const int lane = threadIdx.x & 63;
  const int wv = threadIdx.x >> 6;
  const int grp = lane >> 5;
  const int cbase = (lane & 31) * 8;
  float sc[8], sh[8];
  {
    const float invM = 1.0f / N_NODES;
#pragma unroll
    for (int q = 0; q < 8; ++q) {
      int c = cbase + q;
      float ssum = 0.f, ssq = 0.f;
#pragma unroll
      for (int r2 = 0; r2 < NREP; ++r2) {
        ssum += st[r2 * 512 + c];
        ssq += st[r2 * 512 + 256 + c];
      }
      float mean = ssum * invM;
      float var = ssq * invM - mean * mean;
      float s = g[c] * rsqrtf(var + 1e-5f);
      sc[q] = s;
      sh[q] = bb[c] - mean * s;
    }
  }
  int rowbase = blockIdx.x * 64 + wv * 16;
  int base = rowbase + grp;
  int end = rowbase + 16;
  if (end > N_NODES) end = N_NODES;
  float acc[8] = {};
  int cur = -1;
  for (int r = base; r < end; r += 2) {
    int gg = gid[r];
    if (gg != cur) {
      if (cur >= 0) {
#pragma unroll
        for (int q = 0; q < 8; ++q) {
          atomicAdd(&gp[(size_t)cur * HID + cbase + q], acc[q]);
          acc[q] = 0.f;
        }
      }
      cur = gg;
    }
    u16x8 v = *(const u16x8*)(H + (size_t)r * HID + cbase);
    u16x8 o;
#pragma unroll
    for (int q = 0; q < 8; ++q) {
      float f = b2f(v[q]) * sc[q] + sh[q];
      f = f > 0.f ? f : 0.f;
      acc[q] += f;
      if constexpr (WRITEAPP) o[q] = f2b(f);
    }
    if constexpr (WRITEAPP) *(u16x8*)(happ + (size_t)r * HID + cbase) = o;
  }
  if (cur >= 0) {
#pragma unroll
    for (int q = 0; q < 8; ++q) atomicAdd(&gp[(size_t)cur * HID + cbase + q], acc[q]);
  }
}

// ------- fused: pool raw f32 x into gp0 AND write bf16 copy xb (64 rows/block) -----
__global__ __launch_bounds__(256) void k_xprep(const float* __restrict__ X,
                                               const int* __restrict__ gid,
                                               float* __restrict__ gp,
                                               unsigned short* __restrict__ xb) {
  const int lane = threadIdx.x & 63;
  const int wv = threadIdx.x >> 6;
  const int grp = lane >> 5;
  const int cbase = (lane & 31) * 4;
  int rowbase = blockIdx.x * 64 + wv * 16;
  int base = rowbase + grp;
  int end = rowbase + 16;
  if (end > N_NODES) end = N_NODES;
  float acc[4] = {};
  int cur = -1;
  for (int r = base; r < end; r += 2) {
    int gg = gid[r];
    if (gg != cur) {
      if (cur >= 0) {
#pragma unroll
        for (int q = 0; q < 4; ++q) {
          atomicAdd(&gp[(size_t)cur * INDIM + cbase + q], acc[q]);
          acc[q] = 0.f;
        }
      }
      cur = gg;
    }
    float4 v = *(const float4*)(X + (size_t)r * INDIM + cbase);
    u16x4 o = {f2b(v.x), f2b(v.y), f2b(v.z), f2b(v.w)};
    *(u16x4*)(xb + (size_t)r * INDIM + cbase) = o;
    acc[0] += v.x;
    acc[1] += v.y;
    acc[2] += v.z;
    acc[3] += v.w;
  }
  if (cur >= 0) {
#pragma unroll
    for (int q = 0; q < 4; ++q) atomicAdd(&gp[(size_t)cur * INDIM + cbase + q], acc[q]);
  }
}

// ---------------- final prediction heads ----------------
__global__ __launch_bounds__(256) void k_score(const float* __restrict__ gp0,
                                               const float* __restrict__ gp,
                                               const float* __restrict__ pw0,
                                               const float* __restrict__ pb0,
                                               const float* __restrict__ pw,
                                               const float* __restrict__ pb,
                                               float* __restrict__ out) {
  __shared__ float red[256];
  int g = blockIdx.x;
  int tid = threadIdx.x;
  for (int o = 0; o < OUTD; ++o) {
    float p = 0.f;
    if (tid < INDIM) p += gp0[g * INDIM + tid] * pw0[tid * OUTD + o];
#pragma unroll
    for (int l = 0; l < 4; ++l)
      p += gp[((size_t)l * N_GRAPHS + g) * HID + tid] * pw[(size_t)(l * HID + tid) * OUTD + o];
    red[tid] = p;
    __syncthreads();
    for (int s = 128; s > 0; s >>= 1) {
      if (tid < s) red[tid] += red[tid + s];
      __syncthreads();
    }
    if (tid == 0) {
      float r = red[0] + pb0[o];
      for (int l = 0; l < 4; ++l) r += pb[l * OUTD + o];
      out[g * OUTD + o] = r;
    }
    __syncthreads();
  }
}

extern "C" void kernel_launch(void* const* d_in, const int* in_sizes, int n_in,
                              void* d_out, int out_size, void* d_ws, size_t ws_size,
                              hipStream_t stream) {
  (void)in_sizes; (void)n_in; (void)out_size; (void)ws_size;
  const float* x = (const float*)d_in[0];
  const float* mlp0_w1 = (const float*)d_in[1];
  const float* mlp0_b1 = (const float*)d_in[2];
  const float* mlp0_bng = (const float*)d_in[3];
  const float* mlp0_bnb = (const float*)d_in[4];
  const float* mlp0_w2 = (const float*)d_in[5];
  const float* mlp0_b2 = (const float*)d_in[6];
  const float* mlps_w1 = (const float*)d_in[7];
  const float* mlps_b1 = (const float*)d_in[8];
  const float* mlps_bng = (const float*)d_in[9];
  const float* mlps_bnb = (const float*)d_in[10];
  const float* mlps_w2 = (const float*)d_in[11];
  const float* mlps_b2 = (const float*)d_in[12];
  const float* bng = (const float*)d_in[13];
  const float* bnb = (const float*)d_in[14];
  const float* pw0 = (const float*)d_in[15];
  const float* pb0 = (const float*)d_in[16];
  const float* pw = (const float*)d_in[17];
  const float* pb = (const float*)d_in[18];
  const int* eidx = (const int*)d_in[19];
  const int* gid = (const int*)d_in[20];
  const int* esrc = eidx;
  const int* edst = eidx + N_EDGES;

  char* w = (char*)d_ws;
  size_t off = 0;
  auto take = [&](size_t bytes) -> void* {
    void* p = w + off;
    off += (bytes + 255) & ~(size_t)255;
    return p;
  };
  unsigned short* xb = (unsigned short*)take((size_t)N_NODES * INDIM * 2);
  unsigned short* P0 = (unsigned short*)take((size_t)N_NODES * HID * 2);
  unsigned short* P1 = (unsigned short*)take((size_t)N_NODES * HID * 2);
  unsigned short* P2 = (unsigned short*)take((size_t)N_NODES * HID * 2);
  unsigned short* wt0_1 = (unsigned short*)take((size_t)HID * INDIM * 2);
  unsigned short* wt0_2 = (unsigned short*)take((size_t)HID * HID * 2);
  unsigned short* wts_1 = (unsigned short*)take((size_t)3 * HID * HID * 2);
  unsigned short* wts_2 = (unsigned short*)take((size_t)3 * HID * HID * 2);
  int* deg = (int*)take((size_t)N_NODES * 4);
  int* rowptr = (int*)take((size_t)(N_NODES + 1) * 4);
  int* cursor = (int*)take((size_t)N_NODES * 4);
  int* csr = (int*)take((size_t)N_EDGES * 4);
  int* bsum = (int*)take((size_t)SCAN_NB * 4);
  int* boff = (int*)take((size_t)(SCAN_NB + 1) * 4);
  float* stats = (float*)take((size_t)8 * STSTRIDE * 4);  // 8 stages x 8 replicas x 512
  float* gp0 = (float*)take((size_t)N_GRAPHS * INDIM * 4);
  float* gp = (float*)take((size_t)4 * N_GRAPHS * HID * 4);
  unsigned short* P[3] = {P0, P1, P2};

  hipMemsetAsync(deg, 0, (size_t)N_NODES * 4, stream);
  hipMemsetAsync(stats, 0, (size_t)8 * STSTRIDE * 4, stream);
  hipMemsetAsync(gp0, 0, (size_t)N_GRAPHS * INDIM * 4, stream);
  hipMemsetAsync(gp, 0, (size_t)4 * N_GRAPHS * HID * 4, stream);

  // prep: weight transposes (1 kernel) + CSR build + fused x prep
  k_wt_all<<<(WT_TOTAL + 255) / 256, 256, 0, stream>>>(mlp0_w1, mlp0_w2, mlps_w1, mlps_w2,
                                                       wt0_1, wt0_2, wts_1, wts_2);
  k_hist<<<(N_EDGES + 255) / 256, 256, 0, stream>>>(edst, deg);
  k_scan1<<<SCAN_NB, 256, 0, stream>>>(deg, bsum);
  k_scan2<<<1, 256, 0, stream>>>(bsum, boff);
  k_scan3<<<SCAN_NB, 256, 0, stream>>>(deg, boff, rowptr, cursor);
  k_scatter<<<(N_EDGES + 255) / 256, 256, 0, stream>>>(esrc, edst, cursor, csr);

  const int gemmGrid = ((N_NODES + 127) / 128) * 2;  // 782, 1D (XCD-swizzled)
  const int poolGrid = (N_NODES + 63) / 64;          // 782, ~3 blocks/CU
  const int spmmGrid = (N_NODES + 3) / 4;

  k_xprep<<<poolGrid, 256, 0, stream>>>(x, gid, gp0, xb);

  // Per layer l (buffer rotation): AGG=P[l%3], T1=P[(l+1)%3], RAW=P[(l+2)%3],
  // h_app written back into P[l%3]; spmm input for layer l>=1 is P[(l+2)%3].
  for (int l = 0; l < 4; ++l) {
    unsigned short* AGG = P[l % 3];
    unsigned short* T1 = P[(l + 1) % 3];
    unsigned short* RAW = P[(l + 2) % 3];
    float* st1 = stats + (size_t)(2 * l) * STSTRIDE;
    float* st2 = stats + (size_t)(2 * l + 1) * STSTRIDE;
    if (l == 0) {
      k_spmm5<INDIM><<<spmmGrid, 256, 0, stream>>>(xb, rowptr, csr, AGG);
      k_gemm8<INDIM, false><<<gemmGrid, 256, 0, stream>>>(
          AGG, wt0_1, mlp0_b1, nullptr, nullptr, nullptr, st1, T1, N_NODES);
      k_gemm8<HID, true><<<gemmGrid, 256, 0, stream>>>(
          T1, wt0_2, mlp0_b2, st1, mlp0_bng, mlp0_bnb, st2, RAW, N_NODES);
    } else {
      int li = l - 1;
      k_spmm5<HID><<<spmmGrid, 256, 0, stream>>>(P[(l + 2) % 3], rowptr, csr, AGG);
      k_gemm8<HID, false><<<gemmGrid, 256, 0, stream>>>(
          AGG, wts_1 + (size_t)li * HID * HID, mlps_b1 + li * HID, nullptr, nullptr,
          nullptr, st1, T1, N_NODES);
      k_gemm8<HID, true><<<gemmGrid, 256, 0, stream>>>(
          T1, wts_2 + (size_t)li * HID * HID, mlps_b2 + li * HID, st1,
          mlps_bng + li * HID, mlps_bnb + li * HID, st2, RAW, N_NODES);
    }
    if (l < 3) {
      k_pool_apply<true><<<poolGrid, 256, 0, stream>>>(RAW, gid, st2, bng + l * HID,
                                                       bnb + l * HID,
                                                       gp + (size_t)l * N_GRAPHS * HID,
                                                       P[l % 3]);
    } else {
      k_pool_apply<false><<<poolGrid, 256, 0, stream>>>(RAW, gid, st2, bng + l * HID,
                                                        bnb + l * HID,
                                                        gp + (size_t)l * N_GRAPHS * HID,
                                                        nullptr);
    }
  }

  k_score<<<N_GRAPHS, 256, 0, stream>>>(gp0, gp, pw0, pb0, pw, pb, (float*)d_out);
}

// Round 17
// 686.027 us; speedup vs baseline: 1.3419x; 1.3419x over previous
//
#include <hip/hip_runtime.h>

#define N_NODES 50000
#define N_EDGES 800000
#define N_GRAPHS 64
#define INDIM 128
#define HID 256
#define OUTD 10
#define NREP 8            // stats replicas (atomic-contention spread)
#define STSTRIDE (NREP * 512)
#define PSEG 4            // local graph slots per pool block

typedef __attribute__((ext_vector_type(8))) short bf16x8;
typedef __attribute__((ext_vector_type(4))) float f32x4;
typedef __attribute__((ext_vector_type(4))) unsigned short u16x4;
typedef __attribute__((ext_vector_type(8))) unsigned short u16x8;

__device__ __forceinline__ float b2f(unsigned short u) {
  union { unsigned int i; float f; } c;
  c.i = ((unsigned int)u) << 16;
  return c.f;
}
__device__ __forceinline__ unsigned short f2b(float f) {
  union { float f; unsigned int i; } c;
  c.f = f;
  unsigned int x = c.i + 0x7FFFu + ((c.i >> 16) & 1u);  // RNE
  return (unsigned short)(x >> 16);
}

__device__ __forceinline__ void gload16(const void* g, void* l) {
  __builtin_amdgcn_global_load_lds(
      (const __attribute__((address_space(1))) unsigned int*)g,
      (__attribute__((address_space(3))) unsigned int*)l, 16, 0, 0);
}

// ---------------- CSR build ----------------
__global__ void k_hist(const int* __restrict__ dst, int* __restrict__ deg) {
  int e = blockIdx.x * blockDim.x + threadIdx.x;
  if (e < N_EDGES) atomicAdd(&deg[dst[e]], 1);
}

#define SCAN_NB ((N_NODES + 255) / 256)  // 196

__global__ __launch_bounds__(256) void k_scan1(const int* __restrict__ deg,
                                               int* __restrict__ bsum) {
  int i = blockIdx.x * 256 + threadIdx.x;
  int v = (i < N_NODES) ? deg[i] : 0;
#pragma unroll
  for (int m = 1; m < 64; m <<= 1) v += __shfl_xor(v, m, 64);
  __shared__ int ws[4];
  if ((threadIdx.x & 63) == 0) ws[threadIdx.x >> 6] = v;
  __syncthreads();
  if (threadIdx.x == 0) bsum[blockIdx.x] = ws[0] + ws[1] + ws[2] + ws[3];
}

__global__ __launch_bounds__(256) void k_scan2(const int* __restrict__ bsum,
                                               int* __restrict__ boff) {
  __shared__ int s[256];
  int t = threadIdx.x;
  s[t] = (t < SCAN_NB) ? bsum[t] : 0;
  __syncthreads();
  for (int o = 1; o < 256; o <<= 1) {
    int v = (t >= o) ? s[t - o] : 0;
    __syncthreads();
    s[t] += v;
    __syncthreads();
  }
  if (t < SCAN_NB) boff[t] = (t == 0) ? 0 : s[t - 1];
}

__global__ __launch_bounds__(256) void k_scan3(const int* __restrict__ deg,
                                               const int* __restrict__ boff,
                                               int* __restrict__ rowptr,
                                               int* __restrict__ cursor) {
  __shared__ int s[256];
  int t = threadIdx.x;
  int i = blockIdx.x * 256 + t;
  int v = (i < N_NODES) ? deg[i] : 0;
  s[t] = v;
  __syncthreads();
  for (int o = 1; o < 256; o <<= 1) {
    int w = (t >= o) ? s[t - o] : 0;
    __syncthreads();
    s[t] += w;
    __syncthreads();
  }
  int excl = ((t == 0) ? 0 : s[t - 1]) + boff[blockIdx.x];
  if (i < N_NODES) {
    rowptr[i] = excl;
    cursor[i] = excl;
    if (i == N_NODES - 1) rowptr[N_NODES] = excl + v;
  }
}

__global__ void k_scatter(const int* __restrict__ src, const int* __restrict__ dst,
                          int* __restrict__ cursor, int* __restrict__ csr) {
  int e = blockIdx.x * blockDim.x + threadIdx.x;
  if (e < N_EDGES) {
    int pos = atomicAdd(&cursor[dst[e]], 1);
    csr[pos] = src[e];
  }
}

// ------- all weight transposes in one kernel: W[K][256] f32 -> Wt[256][K] bf16 -----
__global__ __launch_bounds__(256) void k_wt_all(const float* __restrict__ w01,
                                                const float* __restrict__ w02,
                                                const float* __restrict__ ws1,
                                                const float* __restrict__ ws2,
                                                unsigned short* __restrict__ o01,
                                                unsigned short* __restrict__ o02,
                                                unsigned short* __restrict__ os1,
                                                unsigned short* __restrict__ os2) {
  int o = blockIdx.x * 256 + threadIdx.x;
  if (o < 32768) {  // mlp0_w1: K=128
    int c = o >> 7, k = o & 127;
    o01[o] = f2b(w01[k * HID + c]);
    return;
  }
  o -= 32768;
  if (o < 65536) {  // mlp0_w2: K=256
    int c = o >> 8, k = o & 255;
    o02[o] = f2b(w02[k * HID + c]);
    return;
  }
  o -= 65536;
  if (o < 3 * 65536) {  // mlps_w1[3]
    int loc = o & 65535;
    int c = loc >> 8, k = loc & 255;
    os1[o] = f2b(ws1[(size_t)(o >> 16) * 65536 + k * HID + c]);
    return;
  }
  o -= 3 * 65536;
  {
    int loc = o & 65535;
    int c = loc >> 8, k = loc & 255;
    os2[o] = f2b(ws2[(size_t)(o >> 16) * 65536 + k * HID + c]);
  }
}
#define WT_TOTAL (32768 + 65536 + 6 * 65536)  // 491520

// ---------------- SpMM (pure gather-sum) with VALUE prefetch --------------------
template <int DIM>
__global__ __launch_bounds__(256) void k_spmm5(const unsigned short* __restrict__ h,
                                               const int* __restrict__ rowptr,
                                               const int* __restrict__ csr,
                                               unsigned short* __restrict__ out) {
  constexpr int RL = DIM / 8;  // lanes per row (16B each)
  constexpr int NG = 64 / RL;  // concurrent row streams per wave
  const int lane = threadIdx.x & 63;
  const int node = blockIdx.x * 4 + (threadIdx.x >> 6);
  const int grp = lane / RL;
  const int cbase = (lane % RL) * 8;
  const int b = rowptr[node], e = rowptr[node + 1];
  const int count = e - b + 1;  // virtual list: [self] + neighbors
  float acc[8] = {};
  int j = grp;
  int r0 = 0, r1 = 0, r2 = 0, r3 = 0;
  u16x8 v0, v1, v2, v3;
  bool have = (j + 3 * NG < count);
  if (have) {
    r0 = (j == 0) ? node : csr[b + j - 1];
    r1 = csr[b + j + NG - 1];
    r2 = csr[b + j + 2 * NG - 1];
    r3 = csr[b + j + 3 * NG - 1];
    v0 = *(const u16x8*)(h + (size_t)r0 * DIM + cbase);
    v1 = *(const u16x8*)(h + (size_t)r1 * DIM + cbase);
    v2 = *(const u16x8*)(h + (size_t)r2 * DIM + cbase);
    v3 = *(const u16x8*)(h + (size_t)r3 * DIM + cbase);
  }
  while (have) {
    int jn = j + 4 * NG;
    bool haven = (jn + 3 * NG < count);
    u16x8 w0, w1, w2, w3;
    if (haven) {
      int n0 = csr[b + jn - 1];
      int n1 = csr[b + jn + NG - 1];
      int n2 = csr[b + jn + 2 * NG - 1];
      int n3 = csr[b + jn + 3 * NG - 1];
      w0 = *(const u16x8*)(h + (size_t)n0 * DIM + cbase);
      w1 = *(const u16x8*)(h + (size_t)n1 * DIM + cbase);
      w2 = *(const u16x8*)(h + (size_t)n2 * DIM + cbase);
      w3 = *(const u16x8*)(h + (size_t)n3 * DIM + cbase);
    }
#pragma unroll
    for (int q = 0; q < 8; ++q)
      acc[q] += (b2f(v0[q]) + b2f(v1[q])) + (b2f(v2[q]) + b2f(v3[q]));
    v0 = w0; v1 = w1; v2 = w2; v3 = w3;
    j = jn;
    have = haven;
  }
  for (; j < count; j += NG) {
    int rr = (j == 0) ? node : csr[b + j - 1];
    u16x8 t = *(const u16x8*)(h + (size_t)rr * DIM + cbase);
#pragma unroll
    for (int q = 0; q < 8; ++q) acc[q] += b2f(t[q]);
  }
#pragma unroll
  for (int m = RL; m < 64; m <<= 1)
#pragma unroll
    for (int q = 0; q < 8; ++q) acc[q] += __shfl_xor(acc[q], m, 64);
  if (grp == 0) {
    u16x8 o;
#pragma unroll
    for (int q = 0; q < 8; ++q) o[q] = f2b(acc[q]);
    *(u16x8*)(out + (size_t)node * DIM + cbase) = o;
  }
}

// ------- MFMA GEMM, BM=128 x BN=128, dbuf, XCD-swizzled 1D grid, repl-stats -------
template <int K, bool FUSEBN>
__global__ __launch_bounds__(256) void k_gemm8(const unsigned short* __restrict__ A,
                                               const unsigned short* __restrict__ Wt,
                                               const float* __restrict__ bias,
                                               const float* __restrict__ stIn,
                                               const float* __restrict__ gIn,
                                               const float* __restrict__ bIn,
                                               float* __restrict__ stout,
                                               unsigned short* __restrict__ C, int M) {
  constexpr int NT = K / 64;
  __shared__ short As[2][128 * 64];  // 2 x 16 KB
  __shared__ short Bs[2][128 * 64];  // 2 x 16 KB
  __shared__ float s_sum[128], s_sqs[128];
  __shared__ float s_sc[256], s_sh[256];
  const int tid = threadIdx.x;
  const int lane = tid & 63;
  const int wv = tid >> 6;
  const int wm = wv >> 1, wn = wv & 1;  // 2x2 waves, 64x64 quadrant each
  const int l16 = lane & 15, lh = lane >> 4;
  // bijective XCD swizzle: contiguous wgid chunk per XCD
  const int nwg = gridDim.x;
  const int q8 = nwg >> 3, r8 = nwg & 7;
  const int xcd = blockIdx.x & 7, idx8 = blockIdx.x >> 3;
  const int wgid = (xcd < r8 ? xcd * (q8 + 1) : r8 * (q8 + 1) + (xcd - r8) * q8) + idx8;
  const int rB = (wgid >> 1) * 128;
  const int cB = (wgid & 1) * 128;
  f32x4 acc[4][4] = {};
  if (tid < 128) {
    s_sum[tid] = 0.f;
    s_sqs[tid] = 0.f;
  }
  if constexpr (FUSEBN) {
    const float invM = 1.0f / N_NODES;
    float ssum = 0.f, ssq = 0.f;
#pragma unroll
    for (int r2 = 0; r2 < NREP; ++r2) {
      ssum += stIn[r2 * 512 + tid];
      ssq += stIn[r2 * 512 + 256 + tid];
    }
    float mean = ssum * invM;
    float var = ssq * invM - mean * mean;
    float s = gIn[tid] * rsqrtf(var + 1e-5f);
    s_sc[tid] = s;
    s_sh[tid] = bIn[tid] - mean * s;
    __syncthreads();
  }

  auto stageB = [&](int kt, int buf) {
#pragma unroll
    for (int it = 0; it < 4; ++it) {
      int s2 = it * 256 + tid;
      int r = s2 >> 3, g = s2 & 7;
      int gs = g ^ (r & 7);
      gload16(Wt + (size_t)(cB + r) * K + kt * 64 + gs * 8, &Bs[buf][s2 * 8]);
    }
  };
  auto stageA_direct = [&](int kt, int buf) {
#pragma unroll
    for (int it = 0; it < 4; ++it) {
      int s = it * 256 + tid;
      int r = s >> 3, g = s & 7;
      int gs = g ^ (r & 7);
      int row = rB + r;
      if (row > M - 1) row = M - 1;
      gload16(A + (size_t)row * K + kt * 64 + gs * 8, &As[buf][s * 8]);
    }
  };
  auto loadA_reg = [&](int kt, u16x8* va) {
#pragma unroll
    for (int it = 0; it < 4; ++it) {
      int s = it * 256 + tid;
      int r = s >> 3, g = s & 7;
      int gs = g ^ (r & 7);
      int row = rB + r;
      if (row > M - 1) row = M - 1;
      va[it] = *(const u16x8*)(A + (size_t)row * K + kt * 64 + gs * 8);
    }
  };
  auto writeA_bn = [&](int kt, const u16x8* va, int buf) {
#pragma unroll
    for (int it = 0; it < 4; ++it) {
      int s = it * 256 + tid;
      int r = s >> 3, g = s & 7;
      int gs = g ^ (r & 7);
      int ch0 = kt * 64 + gs * 8;
      u16x8 o;
#pragma unroll
      for (int q = 0; q < 8; ++q) {
        float f = b2f(va[it][q]) * s_sc[ch0 + q] + s_sh[ch0 + q];
        o[q] = f2b(f > 0.f ? f : 0.f);
      }
      *(u16x8*)&As[buf][s * 8] = o;
    }
  };
  auto compute = [&](int buf) {
#pragma unroll
    for (int kh = 0; kh < 2; ++kh) {
      bf16x8 af[4], bfr[4];
      const int gsw = (kh * 4 + lh) ^ (l16 & 7);
#pragma unroll
      for (int m = 0; m < 4; ++m) {
        int row = wm * 64 + m * 16 + l16;
        af[m] = *(const bf16x8*)&As[buf][row * 64 + gsw * 8];
      }
#pragma unroll
      for (int n = 0; n < 4; ++n) {
        int col = wn * 64 + n * 16 + l16;
        bfr[n] = *(const bf16x8*)&Bs[buf][col * 64 + gsw * 8];
      }
#pragma unroll
      for (int m = 0; m < 4; ++m)
#pragma unroll
        for (int n = 0; n < 4; ++n)
          acc[m][n] =
              __builtin_amdgcn_mfma_f32_16x16x32_bf16(af[m], bfr[n], acc[m][n], 0, 0, 0);
    }
  };

  // prologue: stage tile 0 into buf 0
  stageB(0, 0);
  if constexpr (!FUSEBN) {
    stageA_direct(0, 0);
  } else {
    u16x8 va0[4];
    loadA_reg(0, va0);
    writeA_bn(0, va0, 0);
  }
  __syncthreads();

  for (int kt = 0; kt < NT; ++kt) {
    const int cur = kt & 1, nxt = cur ^ 1;
    u16x8 va[4];
    const bool more = (kt + 1 < NT);
    if (more) {
      stageB(kt + 1, nxt);
      if constexpr (!FUSEBN) {
        stageA_direct(kt + 1, nxt);
      } else {
        loadA_reg(kt + 1, va);
      }
    }
    compute(cur);
    if constexpr (FUSEBN) {
      if (more) writeA_bn(kt + 1, va, nxt);
    }
    __syncthreads();
  }

  // epilogue: n-inner stores (write-combine friendly) + replicated stats
  float bv[4], ps[4] = {}, pq[4] = {};
#pragma unroll
  for (int n = 0; n < 4; ++n) bv[n] = bias[cB + wn * 64 + n * 16 + l16];
#pragma unroll
  for (int m = 0; m < 4; ++m) {
#pragma unroll
    for (int r = 0; r < 4; ++r) {
      int row = rB + wm * 64 + m * 16 + lh * 4 + r;
      if (row < M) {
#pragma unroll
        for (int n = 0; n < 4; ++n) {
          float val = acc[m][n][r] + bv[n];
          ps[n] += val;
          pq[n] += val * val;
          C[(size_t)row * HID + cB + wn * 64 + n * 16 + l16] = f2b(val);
        }
      }
    }
  }
#pragma unroll
  for (int n = 0; n < 4; ++n) {
    int colL = wn * 64 + n * 16 + l16;
    atomicAdd(&s_sum[colL], ps[n]);
    atomicAdd(&s_sqs[colL], pq[n]);
  }
  __syncthreads();
  if (tid < 128) {
    float* so = stout + (blockIdx.x & (NREP - 1)) * 512;  // replica spread
    atomicAdd(&so[cB + tid], s_sum[tid]);
    atomicAdd(&so[256 + cB + tid], s_sqs[tid]);
  }
}

// ------- pool over relu(bn(raw)) + optional side-output of applied bf16 h ---------
// grid 196 x 256 rows/block. Streams flush into LDS slots keyed by local graph
// index (block spans <=2 graphs at ~780 rows/graph; PSEG=4 slots + global
// fallback), then ONE global atomic per (graph,col) per block.
template <bool WRITEAPP>
__global__ __launch_bounds__(256) void k_pool_apply(const unsigned short* __restrict__ H,
                                                    const int* __restrict__ gid,
                                                    const float* __restrict__ st,
                                                    const float* __restrict__ g,
                                                    const float* __restrict__ bb,
                                                    float* __restrict__ gp,
                                                    unsigned short* __restrict__ happ) {
  __shared__ float s_gp[PSEG][HID];
  __shared__ int s_gbase;
  const int tid = threadIdx.x;
  const int lane = tid & 63;
  const int wv = tid >> 6;
  const int grp = lane >> 5;
  const int cbase = (lane & 31) * 8;
#pragma unroll
  for (int li = 0; li < PSEG; ++li) s_gp[li][tid] = 0.f;
  if (tid == 0) s_gbase = gid[blockIdx.x * 256];
  float sc[8], sh[8];
  {
    const float invM = 1.0f / N_NODES;
#pragma unroll
    for (int q = 0; q < 8; ++q) {
      int c = cbase + q;
      float ssum = 0.f, ssq = 0.f;
#pragma unroll
      for (int r2 = 0; r2 < NREP; ++r2) {
        ssum += st[r2 * 512 + c];
        ssq += st[r2 * 512 + 256 + c];
      }
      float mean = ssum * invM;
      float var = ssq * invM - mean * mean;
      float s = g[c] * rsqrtf(var + 1e-5f);
      sc[q] = s;
      sh[q] = bb[c] - mean * s;
    }
  }
  __syncthreads();
  const int gbase = s_gbase;
  auto flush = [&](int cur, const float* acc) {
    int li = cur - gbase;
    if (li < PSEG) {
#pragma unroll
      for (int q = 0; q < 8; ++q) atomicAdd(&s_gp[li][cbase + q], acc[q]);
    } else {
#pragma unroll
      for (int q = 0; q < 8; ++q) atomicAdd(&gp[(size_t)cur * HID + cbase + q], acc[q]);
    }
  };
  int base = blockIdx.x * 256 + wv * 64 + grp;
  int end = blockIdx.x * 256 + wv * 64 + 64;
  if (end > N_NODES) end = N_NODES;
  float acc[8] = {};
  int cur = -1;
  for (int r = base; r < end; r += 2) {
    int gg = gid[r];
    if (gg != cur) {
      if (cur >= 0) {
        flush(cur, acc);
#pragma unroll
        for (int q = 0; q < 8; ++q) acc[q] = 0.f;
      }
      cur = gg;
    }
    u16x8 v = *(const u16x8*)(H + (size_t)r * HID + cbase);
    u16x8 o;
#pragma unroll
    for (int q = 0; q < 8; ++q) {
      float f = b2f(v[q]) * sc[q] + sh[q];
      f = f > 0.f ? f : 0.f;
      acc[q] += f;
      if constexpr (WRITEAPP) o[q] = f2b(f);
    }
    if constexpr (WRITEAPP) *(u16x8*)(happ + (size_t)r * HID + cbase) = o;
  }
  if (cur >= 0) flush(cur, acc);
  __syncthreads();
  // drain: one global atomic per (graph,col) per block; skip exact zeros
#pragma unroll
  for (int li = 0; li < PSEG; ++li) {
    int gg = gbase + li;
    if (gg < N_GRAPHS) {
      float v = s_gp[li][tid];
      if (v != 0.f) atomicAdd(&gp[(size_t)gg * HID + tid], v);
    }
  }
}

// ------- fused: pool raw f32 x into gp0 AND write bf16 copy xb (LDS-accum) --------
__global__ __launch_bounds__(256) void k_xprep(const float* __restrict__ X,
                                               const int* __restrict__ gid,
                                               float* __restrict__ gp,
                                               unsigned short* __restrict__ xb) {
  __shared__ float s_gp[PSEG][INDIM];
  __shared__ int s_gbase;
  const int tid = threadIdx.x;
  const int lane = tid & 63;
  const int wv = tid >> 6;
  const int grp = lane >> 5;
  const int cbase = (lane & 31) * 4;
  if (tid < INDIM) {
#pragma unroll
    for (int li = 0; li < PSEG; ++li) s_gp[li][tid] = 0.f;
  }
  if (tid == 0) s_gbase = gid[blockIdx.x * 256];
  __syncthreads();
  const int gbase = s_gbase;
  auto flush = [&](int cur, const float* acc) {
    int li = cur - gbase;
    if (li < PSEG) {
#pragma unroll
      for (int q = 0; q < 4; ++q) atomicAdd(&s_gp[li][cbase + q], acc[q]);
    } else {
#pragma unroll
      for (int q = 0; q < 4; ++q) atomicAdd(&gp[(size_t)cur * INDIM + cbase + q], acc[q]);
    }
  };
  int base = blockIdx.x * 256 + wv * 64 + grp;
  int end = blockIdx.x * 256 + wv * 64 + 64;
  if (end > N_NODES) end = N_NODES;
  float acc[4] = {};
  int cur = -1;
  for (int r = base; r < end; r += 2) {
    int gg = gid[r];
    if (gg != cur) {
      if (cur >= 0) {
        flush(cur, acc);
#pragma unroll
        for (int q = 0; q < 4; ++q) acc[q] = 0.f;
      }
      cur = gg;
    }
    float4 v = *(const float4*)(X + (size_t)r * INDIM + cbase);
    u16x4 o = {f2b(v.x), f2b(v.y), f2b(v.z), f2b(v.w)};
    *(u16x4*)(xb + (size_t)r * INDIM + cbase) = o;
    acc[0] += v.x;
    acc[1] += v.y;
    acc[2] += v.z;
    acc[3] += v.w;
  }
  if (cur >= 0) flush(cur, acc);
  __syncthreads();
  if (tid < INDIM) {
#pragma unroll
    for (int li = 0; li < PSEG; ++li) {
      int gg = gbase + li;
      if (gg < N_GRAPHS) {
        float v = s_gp[li][tid];
        if (v != 0.f) atomicAdd(&gp[(size_t)gg * INDIM + tid], v);
      }
    }
  }
}

// ---------------- final prediction heads ----------------
__global__ __launch_bounds__(256) void k_score(const float* __restrict__ gp0,
                                               const float* __restrict__ gp,
                                               const float* __restrict__ pw0,
                                               const float* __restrict__ pb0,
                                               const float* __restrict__ pw,
                                               const float* __restrict__ pb,
                                               float* __restrict__ out) {
  __shared__ float red[256];
  int g = blockIdx.x;
  int tid = threadIdx.x;
  for (int o = 0; o < OUTD; ++o) {
    float p = 0.f;
    if (tid < INDIM) p += gp0[g * INDIM + tid] * pw0[tid * OUTD + o];
#pragma unroll
    for (int l = 0; l < 4; ++l)
      p += gp[((size_t)l * N_GRAPHS + g) * HID + tid] * pw[(size_t)(l * HID + tid) * OUTD + o];
    red[tid] = p;
    __syncthreads();
    for (int s = 128; s > 0; s >>= 1) {
      if (tid < s) red[tid] += red[tid + s];
      __syncthreads();
    }
    if (tid == 0) {
      float r = red[0] + pb0[o];
      for (int l = 0; l < 4; ++l) r += pb[l * OUTD + o];
      out[g * OUTD + o] = r;
    }
    __syncthreads();
  }
}

extern "C" void kernel_launch(void* const* d_in, const int* in_sizes, int n_in,
                              void* d_out, int out_size, void* d_ws, size_t ws_size,
                              hipStream_t stream) {
  (void)in_sizes; (void)n_in; (void)out_size; (void)ws_size;
  const float* x = (const float*)d_in[0];
  const float* mlp0_w1 = (const float*)d_in[1];
  const float* mlp0_b1 = (const float*)d_in[2];
  const float* mlp0_bng = (const float*)d_in[3];
  const float* mlp0_bnb = (const float*)d_in[4];
  const float* mlp0_w2 = (const float*)d_in[5];
  const float* mlp0_b2 = (const float*)d_in[6];
  const float* mlps_w1 = (const float*)d_in[7];
  const float* mlps_b1 = (const float*)d_in[8];
  const float* mlps_bng = (const float*)d_in[9];
  const float* mlps_bnb = (const float*)d_in[10];
  const float* mlps_w2 = (const float*)d_in[11];
  const float* mlps_b2 = (const float*)d_in[12];
  const float* bng = (const float*)d_in[13];
  const float* bnb = (const float*)d_in[14];
  const float* pw0 = (const float*)d_in[15];
  const float* pb0 = (const float*)d_in[16];
  const float* pw = (const float*)d_in[17];
  const float* pb = (const float*)d_in[18];
  const int* eidx = (const int*)d_in[19];
  const int* gid = (const int*)d_in[20];
  const int* esrc = eidx;
  const int* edst = eidx + N_EDGES;

  char* w = (char*)d_ws;
  size_t off = 0;
  auto take = [&](size_t bytes) -> void* {
    void* p = w + off;
    off += (bytes + 255) & ~(size_t)255;
    return p;
  };
  unsigned short* xb = (unsigned short*)take((size_t)N_NODES * INDIM * 2);
  unsigned short* P0 = (unsigned short*)take((size_t)N_NODES * HID * 2);
  unsigned short* P1 = (unsigned short*)take((size_t)N_NODES * HID * 2);
  unsigned short* P2 = (unsigned short*)take((size_t)N_NODES * HID * 2);
  unsigned short* wt0_1 = (unsigned short*)take((size_t)HID * INDIM * 2);
  unsigned short* wt0_2 = (unsigned short*)take((size_t)HID * HID * 2);
  unsigned short* wts_1 = (unsigned short*)take((size_t)3 * HID * HID * 2);
  unsigned short* wts_2 = (unsigned short*)take((size_t)3 * HID * HID * 2);
  int* deg = (int*)take((size_t)N_NODES * 4);
  int* rowptr = (int*)take((size_t)(N_NODES + 1) * 4);
  int* cursor = (int*)take((size_t)N_NODES * 4);
  int* csr = (int*)take((size_t)N_EDGES * 4);
  int* bsum = (int*)take((size_t)SCAN_NB * 4);
  int* boff = (int*)take((size_t)(SCAN_NB + 1) * 4);
  float* stats = (float*)take((size_t)8 * STSTRIDE * 4);  // 8 stages x 8 replicas x 512
  float* gp0 = (float*)take((size_t)N_GRAPHS * INDIM * 4);
  float* gp = (float*)take((size_t)4 * N_GRAPHS * HID * 4);
  unsigned short* P[3] = {P0, P1, P2};

  hipMemsetAsync(deg, 0, (size_t)N_NODES * 4, stream);
  hipMemsetAsync(stats, 0, (size_t)8 * STSTRIDE * 4, stream);
  hipMemsetAsync(gp0, 0, (size_t)N_GRAPHS * INDIM * 4, stream);
  hipMemsetAsync(gp, 0, (size_t)4 * N_GRAPHS * HID * 4, stream);

  // prep: weight transposes (1 kernel) + CSR build + fused x prep
  k_wt_all<<<(WT_TOTAL + 255) / 256, 256, 0, stream>>>(mlp0_w1, mlp0_w2, mlps_w1, mlps_w2,
                                                       wt0_1, wt0_2, wts_1, wts_2);
  k_hist<<<(N_EDGES + 255) / 256, 256, 0, stream>>>(edst, deg);
  k_scan1<<<SCAN_NB, 256, 0, stream>>>(deg, bsum);
  k_scan2<<<1, 256, 0, stream>>>(bsum, boff);
  k_scan3<<<SCAN_NB, 256, 0, stream>>>(deg, boff, rowptr, cursor);
  k_scatter<<<(N_EDGES + 255) / 256, 256, 0, stream>>>(esrc, edst, cursor, csr);

  const int gemmGrid = ((N_NODES + 127) / 128) * 2;  // 782, 1D (XCD-swizzled)
  const int poolGrid = (N_NODES + 255) / 256;        // 196
  const int spmmGrid = (N_NODES + 3) / 4;

  k_xprep<<<poolGrid, 256, 0, stream>>>(x, gid, gp0, xb);

  // Per layer l (buffer rotation): AGG=P[l%3], T1=P[(l+1)%3], RAW=P[(l+2)%3],
  // h_app written back into P[l%3]; spmm input for layer l>=1 is P[(l+2)%3].
  for (int l = 0; l < 4; ++l) {
    unsigned short* AGG = P[l % 3];
    unsigned short* T1 = P[(l + 1) % 3];
    unsigned short* RAW = P[(l + 2) % 3];
    float* st1 = stats + (size_t)(2 * l) * STSTRIDE;
    float* st2 = stats + (size_t)(2 * l + 1) * STSTRIDE;
    if (l == 0) {
      k_spmm5<INDIM><<<spmmGrid, 256, 0, stream>>>(xb, rowptr, csr, AGG);
      k_gemm8<INDIM, false><<<gemmGrid, 256, 0, stream>>>(
          AGG, wt0_1, mlp0_b1, nullptr, nullptr, nullptr, st1, T1, N_NODES);
      k_gemm8<HID, true><<<gemmGrid, 256, 0, stream>>>(
          T1, wt0_2, mlp0_b2, st1, mlp0_bng, mlp0_bnb, st2, RAW, N_NODES);
    } else {
      int li = l - 1;
      k_spmm5<HID><<<spmmGrid, 256, 0, stream>>>(P[(l + 2) % 3], rowptr, csr, AGG);
      k_gemm8<HID, false><<<gemmGrid, 256, 0, stream>>>(
          AGG, wts_1 + (size_t)li * HID * HID, mlps_b1 + li * HID, nullptr, nullptr,
          nullptr, st1, T1, N_NODES);
      k_gemm8<HID, true><<<gemmGrid, 256, 0, stream>>>(
          T1, wts_2 + (size_t)li * HID * HID, mlps_b2 + li * HID, st1,
          mlps_bng + li * HID, mlps_bnb + li * HID, st2, RAW, N_NODES);
    }
    if (l < 3) {
      k_pool_apply<true><<<poolGrid, 256, 0, stream>>>(RAW, gid, st2, bng + l * HID,
                                                       bnb + l * HID,
                                                       gp + (size_t)l * N_GRAPHS * HID,
                                                       P[l % 3]);
    } else {
      k_pool_apply<false><<<poolGrid, 256, 0, stream>>>(RAW, gid, st2, bng + l * HID,
                                                        bnb + l * HID,
                                                        gp + (size_t)l * N_GRAPHS * HID,
                                                        nullptr);
    }
  }

  k_score<<<N_GRAPHS, 256, 0, stream>>>(gp0, gp, pw0, pb0, pw, pb, (float*)d_out);
}